// Round 16
// baseline (171.556 us; speedup 1.0000x reference)
//
#include <hip/hip_runtime.h>
#include <stdint.h>

// Problem constants (fixed by the reference)
#define BN    8192    // batch
#define DK    256     // dim
#define PN    4096    // pairs
#define MAXP  16      // max partners tracked per row (Poisson(1); P(>16) ~ 1e-15)
#define RANK_ASC 6553 // ascending rank of first kept element (top-1639 = 0.8 quantile)
#define QSTEP 0.02f   // logit quantization step: code = round(5*cos/QSTEP)+128 in [1,255]

typedef float    f32x4 __attribute__((ext_vector_type(4)));
typedef int      i32x4 __attribute__((ext_vector_type(4)));
typedef unsigned u32x4 __attribute__((ext_vector_type(4)));

__device__ __forceinline__ void gload_lds16(const void* g, void* l) {
  __builtin_amdgcn_global_load_lds(
      (const __attribute__((address_space(1))) unsigned int*)g,
      (__attribute__((address_space(3))) unsigned int*)l, 16, 0, 0);
}

// ------------------------------------------------ parallel bin finder (256 bins)
__device__ __forceinline__ void find_bin_256(const unsigned* hist, int rank,
                                             int* sh, unsigned* wtot) {
  const int tid = threadIdx.x, lane = tid & 63, w = tid >> 6;
  unsigned x = hist[tid];
  unsigned pref = x;
  #pragma unroll
  for (int o = 1; o < 64; o <<= 1) {
    unsigned y = __shfl_up(pref, o);
    if (lane >= o) pref += y;
  }
  if (lane == 63) wtot[w] = pref;
  __syncthreads();
  unsigned woff = 0;
  for (int i = 0; i < w; ++i) woff += wtot[i];
  unsigned incl = pref + woff, excl = incl - x;
  if ((unsigned)rank >= excl && (unsigned)rank < incl) { sh[0] = tid; sh[1] = rank - (int)excl; }
  __syncthreads();
}

__device__ __forceinline__ float block_sum4(float x, float* red4) {
  const int lane = threadIdx.x & 63, w = threadIdx.x >> 6;
  #pragma unroll
  for (int o = 32; o; o >>= 1) x += __shfl_xor(x, o);
  __syncthreads();
  if (lane == 0) red4[w] = x;
  __syncthreads();
  return red4[0] + red4[1] + red4[2] + red4[3];
}

// ---------------- K1: normalize -> int8 (1 row/wave) + pair scatter + first-touch compact ----
__global__ void __launch_bounds__(256) norm_pairs_kernel(
    const float* __restrict__ X, signed char* __restrict__ Ei8,
    const int2* __restrict__ pairs, int* pcount, int* partners,
    int* rowlist, int* cnt) {
  const int tid  = threadIdx.x;
  const int lane = tid & 63;
  const int wib  = tid >> 6;
  const int row  = blockIdx.x * 4 + wib;      // grid 2048 -> rows 0..8191

  float4 x = ((const float4*)(X + (size_t)row * DK))[lane];
  float ss = x.x * x.x + x.y * x.y + x.z * x.z + x.w * x.w;
  #pragma unroll
  for (int o = 32; o; o >>= 1) ss += __shfl_xor(ss, o);
  float inv = 127.0f / fmaxf(sqrtf(ss), 1e-8f);
  int c0 = (int)rintf(inv * x.x);
  int c1 = (int)rintf(inv * x.y);
  int c2 = (int)rintf(inv * x.z);
  int c3 = (int)rintf(inv * x.w);
  unsigned u = (unsigned)(c0 & 255) | ((unsigned)(c1 & 255) << 8)
             | ((unsigned)(c2 & 255) << 16) | ((unsigned)(c3 & 255) << 24);
  ((unsigned*)(Ei8 + (size_t)row * DK))[lane] = u;

  const int p = blockIdx.x * 256 + tid;
  if (p < PN) {
    int2 pr = pairs[p];
    int ix = atomicAdd(&pcount[pr.x], 1);
    if (ix == 0) { int q = atomicAdd(cnt, 1); rowlist[q] = pr.x; }   // first touch
    if (ix < MAXP) partners[pr.x * MAXP + ix] = pr.y;
    int iy = atomicAdd(&pcount[pr.y], 1);
    if (iy == 0) { int q = atomicAdd(cnt, 1); rowlist[q] = pr.y; }
    if (iy < MAXP) partners[pr.y * MAXP + iy] = pr.x;
  }
}

// ---------------- K2: pos (1 pair/wave, int8 dot) ----------------
__global__ void __launch_bounds__(256) pos_kernel(
    const signed char* __restrict__ Ei8, const int2* __restrict__ pairs,
    float* __restrict__ pos) {
  const int tid  = threadIdx.x;
  const int lane = tid & 63;
  const int wib  = tid >> 6;
  const int p    = blockIdx.x * 4 + wib;      // grid 1024 -> pairs 0..4095
  int2 pr = pairs[p];
  int a = ((const int*)(Ei8 + (size_t)pr.x * DK))[lane];
  int b = ((const int*)(Ei8 + (size_t)pr.y * DK))[lane];
  int s = 0;
  #pragma unroll
  for (int j = 0; j < 4; ++j) {
    int va = (int)(signed char)(a >> (8 * j));
    int vb = (int)(signed char)(b >> (8 * j));
    s += va * vb;
  }
  #pragma unroll
  for (int o = 32; o; o >>= 1) s += __shfl_xor(s, o);
  if (lane == 0) pos[p] = __expf((float)s * (5.0f / 16129.0f));
}

// ---------------- K3: int8 GEMM, BK=128 -> logit codes ----------------
// dot_i32 = sum Ei8[row].Ei8[col]; cos = dot/127^2.
// code = clamp(trunc(dot*(250/16129) + 128.5), 1, 255); 0 reserved for masked.
// Interleaved out: dword [rowgroup][col] = rows 4g..4g+3 (byte=row%4).
// 128x128 tile, BK=128 (2 K-iters -> 4 barriers), mfma_i32_16x16x64_i8,
// global_load_lds(16B), LDS slot swizzle sl = sg ^ (row&7), NT stores.
__global__ void __launch_bounds__(256) gemm_code_kernel(
    const signed char* __restrict__ Ei8, const int* __restrict__ rowlist,
    const int* __restrict__ countp, uint32_t* __restrict__ out4) {
  if ((int)blockIdx.y * 128 >= *countp) return;
  __shared__ __align__(16) signed char sA[128 * 128];   // 16 KB
  __shared__ __align__(16) signed char sB[128 * 128];   // 16 KB
  const int tid  = threadIdx.x;
  const int lane = tid & 63;
  const int w    = tid >> 6;
  const int wm   = w >> 1, wn = w & 1;
  const int trow = blockIdx.y * 128;
  const int tcol = blockIdx.x * 128;

  const int srow = tid >> 3;
  const int sl   = tid & 7;
  const int sg   = sl ^ (srow & 7);
  int garow[4], gbrow[4];
  #pragma unroll
  for (int ii = 0; ii < 4; ++ii) {
    garow[ii] = rowlist[trow + ii * 32 + srow];
    gbrow[ii] = tcol + ii * 32 + srow;
  }

  i32x4 acc[4][4];
  #pragma unroll
  for (int i = 0; i < 4; ++i)
    #pragma unroll
    for (int j = 0; j < 4; ++j) {
      i32x4 z = {0, 0, 0, 0};
      acc[i][j] = z;
    }

  for (int kt = 0; kt < 2; ++kt) {
    const int k0 = kt * 128;
    __syncthreads();
    #pragma unroll
    for (int ii = 0; ii < 4; ++ii) {
      gload_lds16(Ei8 + (size_t)garow[ii] * DK + k0 + sg * 16, &sA[ii * 4096 + tid * 16]);
      gload_lds16(Ei8 + (size_t)gbrow[ii] * DK + k0 + sg * 16, &sB[ii * 4096 + tid * 16]);
    }
    __syncthreads();
    #pragma unroll
    for (int h = 0; h < 2; ++h) {
      const int fg = h * 4 + (lane >> 4);     // k-segment 0..7 (16 i8 each)
      i32x4 af[4], bfg[4];
      #pragma unroll
      for (int q = 0; q < 4; ++q) {
        const int ra = wm * 64 + q * 16 + (lane & 15);
        const int rb = wn * 64 + q * 16 + (lane & 15);
        af[q]  = *(const i32x4*)&sA[ra * 128 + (fg ^ (ra & 7)) * 16];
        bfg[q] = *(const i32x4*)&sB[rb * 128 + (fg ^ (rb & 7)) * 16];
      }
      #pragma unroll
      for (int i = 0; i < 4; ++i)
        #pragma unroll
        for (int j = 0; j < 4; ++j)
          acc[i][j] = __builtin_amdgcn_mfma_i32_16x16x64_i8(af[i], bfg[j], acc[i][j], 0, 0, 0);
    }
  }

  const int crow = trow + wm * 64 + (lane >> 4) * 4;  // %4 == 0
  const int ccol = tcol + wn * 64 + (lane & 15);
  const float SCL = 250.0f / 16129.0f;                // (1/beta)/(127^2) in code units
  #pragma unroll
  for (int i = 0; i < 4; ++i) {
    const int gidx = (crow + i * 16) >> 2;
    #pragma unroll
    for (int j = 0; j < 4; ++j) {
      const int col = ccol + j * 16;
      uint32_t u = 0;
      #pragma unroll
      for (int r = 0; r < 4; ++r) {
        int c = (int)fmaf((float)acc[i][j][r], SCL, 128.5f);
        c = c < 1 ? 1 : (c > 255 ? 255 : c);
        u |= (uint32_t)c << (8 * r);
      }
      __builtin_nontemporal_store(u, &out4[(size_t)gidx * BN + col]);   // write-once stream
    }
  }
}

// ---------------- K4: row stats + fused finale (last-block-done) ----------------
// One block per group of 4 compacted rows; code byte == radix bin; one hist
// pass, exact select on quantized values: S = sum_{bin>b} cnt*val + need*val(b).
// After S writes: device-scope release fence + atomicAdd(done); the LAST active
// block (old == nact-1) acquires and runs the finale (radix-select pos rank 819
// -> thr; factorized loss from log1p(S/p) = logS - logp + p/S - p^2/(2S^2)).
__global__ void __launch_bounds__(256) row_stats4_kernel(
    const uint32_t* __restrict__ expc4, const int* __restrict__ rowlist,
    const int* __restrict__ countp, const int* __restrict__ pcount,
    const int* __restrict__ partners, float* __restrict__ S,
    int* done, const float* __restrict__ pos, const int2* __restrict__ pairs,
    float* __restrict__ out) {
  __shared__ unsigned hist[4][4][256];   // [wave][r4][bin] = 16 KB (finale: aliases v[4096])
  __shared__ unsigned total[4][256];     // 4 KB              (finale: total[0] = hist256)
  __shared__ int plist[4][MAXP + 1];
  __shared__ int npl[4];
  __shared__ int growl[4];
  __shared__ int sh[2];
  __shared__ unsigned wtot[4];
  __shared__ float redf[4];
  const int g = blockIdx.x;
  const int cnt = *countp;
  if (g * 4 >= cnt) return;
  const int nact = (cnt + 3) >> 2;       // # active blocks
  const int tid = threadIdx.x, lane = tid & 63, w = tid >> 6;

  u32x4 rv[8];
  const u32x4* src = (const u32x4*)(expc4 + (size_t)g * BN);
  #pragma unroll
  for (int q = 0; q < 8; ++q) rv[q] = __builtin_nontemporal_load(&src[q * 256 + tid]);

  if (tid < 4) {
    int rr = g * 4 + tid;
    int grow = (rr < cnt) ? rowlist[rr] : -1;
    growl[tid] = grow;
    int np = 0;
    if (grow >= 0) {
      np = pcount[grow]; if (np > MAXP) np = MAXP;
      for (int e = 0; e < np; ++e) plist[tid][e] = partners[grow * MAXP + e];
      plist[tid][np] = grow;   // diagonal
      np++;
    }
    npl[tid] = np;
  }
  #pragma unroll
  for (int k = 0; k < 16; ++k) ((unsigned*)hist)[k * 256 + tid] = 0;
  __syncthreads();

  // mask partner/diagonal columns (zero byte -> bin 0, never selected)
  #pragma unroll
  for (int r4 = 0; r4 < 4; ++r4) {
    const int np = npl[r4];
    for (int e = 0; e < np; ++e) {
      int c = plist[r4][e];
      int t = c >> 2;
      if ((t & 255) == tid) {
        unsigned* wp = (unsigned*)&rv[t >> 8];
        wp[c & 3] &= ~(0xFFu << (r4 * 8));
      }
    }
  }

  unsigned* h = (unsigned*)hist[w];
  #pragma unroll
  for (int q = 0; q < 8; ++q) {
    #pragma unroll
    for (int word = 0; word < 4; ++word) {
      unsigned dw = ((const unsigned*)&rv[q])[word];
      atomicAdd(&h[0 * 256 + (dw & 255u)], 1u);
      atomicAdd(&h[1 * 256 + ((dw >> 8) & 255u)], 1u);
      atomicAdd(&h[2 * 256 + ((dw >> 16) & 255u)], 1u);
      atomicAdd(&h[3 * 256 + (dw >> 24)], 1u);
    }
  }
  __syncthreads();
  #pragma unroll
  for (int r4 = 0; r4 < 4; ++r4)
    total[r4][tid] = hist[0][r4][tid] + hist[1][r4][tid] + hist[2][r4][tid] + hist[3][r4][tid];
  __syncthreads();

  const float val = __expf((float)(tid - 128) * QSTEP);
  for (int r4 = 0; r4 < 4; ++r4) {
    find_bin_256(total[r4], RANK_ASC, sh, wtot);
    const int b    = sh[0];
    const int need = (int)total[r4][b] - sh[1];
    float contrib = (tid > b) ? (float)total[r4][tid] * val
                  : (tid == b) ? (float)need * val : 0.f;
    #pragma unroll
    for (int o = 32; o; o >>= 1) contrib += __shfl_xor(contrib, o);
    __syncthreads();
    if (lane == 0) redf[w] = contrib;
    __syncthreads();
    if (tid == 0 && growl[r4] >= 0)
      S[growl[r4]] = redf[0] + redf[1] + redf[2] + redf[3];
    __syncthreads();
  }

  // ---- last-block election (release on writers, acquire on reader) ----
  if (tid == 0) {
    __threadfence();                       // flush this block's S writes to device scope
    int old = atomicAdd(done, 1);          // device-scope by default [m20]
    sh[0] = (old == nact - 1) ? 1 : 0;
  }
  __syncthreads();
  if (!sh[0]) return;
  __threadfence();                         // acquire: invalidate stale L1/L2 lines

  // ---- finale (runs in the single elected block; LDS reused) ----
  unsigned* v     = (unsigned*)hist;       // 4096 u32 = 16 KB
  unsigned* fhist = total[0];              // 256 bins
  __syncthreads();
  for (int i = tid; i < PN; i += 256) v[i] = ((const unsigned*)pos)[i];
  __syncthreads();
  int rank = 819;                          // 0.2 * 4095 exactly
  uint32_t prefix = 0;
  for (int pass = 0; pass < 4; ++pass) {
    const int shift = 24 - pass * 8;
    fhist[tid] = 0;
    __syncthreads();
    for (int i = tid; i < PN; i += 256) {
      uint32_t x = v[i];
      bool match = (pass == 0) || ((x >> (shift + 8)) == (prefix >> (shift + 8)));
      if (match) atomicAdd(&fhist[(x >> shift) & 255u], 1u);
    }
    __syncthreads();
    find_bin_256(fhist, rank, sh, wtot);
    prefix |= ((uint32_t)sh[0]) << shift;
    rank = sh[1];
    __syncthreads();
  }
  float thr; __builtin_memcpy(&thr, &prefix, 4);

  float n = 0.f, slg = 0.f, sp = 0.f, sp2 = 0.f;
  for (int r = tid; r < PN; r += 256) {
    float p; uint32_t b = v[r]; __builtin_memcpy(&p, &b, 4);
    if (p <= thr) { n += 1.f; slg += __logf(p); sp += p; sp2 += p * p; }
  }
  float t = 0.f, u = 0.f, vv = 0.f;
  for (int c = tid; c < PN; c += 256) {
    int2 pr = pairs[c];
    float s1 = S[pr.x], s2 = S[pr.y];
    float i1 = 1.f / s1, i2 = 1.f / s2;
    t += __logf(s1) + __logf(s2);
    u += i1 + i2;
    vv += i1 * i1 + i2 * i2;
  }
  const float N   = block_sum4(n, redf);
  const float SL  = block_sum4(slg, redf);
  const float SP  = block_sum4(sp, redf);
  const float SP2 = block_sum4(sp2, redf);
  const float T   = block_sum4(t, redf);
  const float U   = block_sum4(u, redf);
  const float V   = block_sum4(vv, redf);
  if (tid == 0) {
    double num = (double)N * T - 2.0 * (double)PN * (double)SL
               + (double)SP * U - 0.5 * (double)SP2 * V;
    out[0] = (float)(num / (2.0 * (double)PN));
  }
}

// ---------------------------------------------------------------- launch
extern "C" void kernel_launch(void* const* d_in, const int* in_sizes, int n_in,
                              void* d_out, int out_size, void* d_ws, size_t ws_size,
                              hipStream_t stream) {
  const float* emb  = (const float*)d_in[0];
  const int2* pairs = (const int2*)d_in[1];
  float* out = (float*)d_out;

  // ws layout: [pcnt | rlist | cnt/done block] contiguous -> ONE memset clears all.
  // NOTE: cnt is int*, so done = cnt + 1 is byte offset 4 — INSIDE the cleared
  // 256-byte block. (R15 bug: cnt + 64 = byte 256 = past the block, aliasing Ei8.)
  char* w = (char*)d_ws;
  size_t off = 0;
  int*         pcnt  = (int*)(w + off);         off += (size_t)BN * 4;
  int*         rlist = (int*)(w + off);         off += (size_t)BN * 4;
  int*         cnt   = (int*)(w + off);         off += 256;   // cnt at int[0], done at int[1]
  signed char* Ei8   = (signed char*)(w + off); off += (size_t)BN * DK;      // 2 MB
  float*       S     = (float*)(w + off);       off += (size_t)BN * 4;
  float*       pos   = (float*)(w + off);       off += (size_t)PN * 4;
  int*         parts = (int*)(w + off);         off += (size_t)BN * MAXP * 4; // 512 KB
  uint32_t*    out4  = (uint32_t*)(w + off);    off += (size_t)(BN / 4) * BN * 4; // 67 MB
  int*         done  = cnt + 1;

  hipMemsetAsync(pcnt, 0, (size_t)BN * 8 + 256, stream);   // pcnt + rlist + cnt + done
  norm_pairs_kernel<<<BN / 4, 256, 0, stream>>>(emb, Ei8, pairs, pcnt, parts, rlist, cnt);
  pos_kernel<<<PN / 4, 256, 0, stream>>>(Ei8, pairs, pos);
  gemm_code_kernel<<<dim3(BN / 128, BN / 128), 256, 0, stream>>>(Ei8, rlist, cnt, out4);
  row_stats4_kernel<<<BN / 4, 256, 0, stream>>>(out4, rlist, cnt, pcnt, parts, S,
                                                done, pos, pairs, out);
}

// Round 17
// 148.182 us; speedup vs baseline: 1.1577x; 1.1577x over previous
//
#include <hip/hip_runtime.h>
#include <stdint.h>

// Problem constants (fixed by the reference)
#define BN    8192    // batch
#define DK    256     // dim
#define PN    4096    // pairs
#define MAXP  16      // max partners tracked per row (Poisson(1); P(>16) ~ 1e-15)
#define RANK_ASC 6553 // ascending rank of first kept element (top-1639 = 0.8 quantile)
#define QSTEP 0.02f   // logit quantization step: code = round(5*cos/QSTEP)+128 in [1,255]

typedef float f32x4  __attribute__((ext_vector_type(4)));
typedef int   i32x4  __attribute__((ext_vector_type(4)));

__device__ __forceinline__ void gload_lds16(const void* g, void* l) {
  __builtin_amdgcn_global_load_lds(
      (const __attribute__((address_space(1))) unsigned int*)g,
      (__attribute__((address_space(3))) unsigned int*)l, 16, 0, 0);
}

// ------------------------------------------------ parallel bin finder (256 bins)
__device__ __forceinline__ void find_bin_256(const unsigned* hist, int rank,
                                             int* sh, unsigned* wtot) {
  const int tid = threadIdx.x, lane = tid & 63, w = tid >> 6;
  unsigned x = hist[tid];
  unsigned pref = x;
  #pragma unroll
  for (int o = 1; o < 64; o <<= 1) {
    unsigned y = __shfl_up(pref, o);
    if (lane >= o) pref += y;
  }
  if (lane == 63) wtot[w] = pref;
  __syncthreads();
  unsigned woff = 0;
  for (int i = 0; i < w; ++i) woff += wtot[i];
  unsigned incl = pref + woff, excl = incl - x;
  if ((unsigned)rank >= excl && (unsigned)rank < incl) { sh[0] = tid; sh[1] = rank - (int)excl; }
  __syncthreads();
}

__device__ __forceinline__ float block_sum4(float x, float* red4) {
  const int lane = threadIdx.x & 63, w = threadIdx.x >> 6;
  #pragma unroll
  for (int o = 32; o; o >>= 1) x += __shfl_xor(x, o);
  __syncthreads();
  if (lane == 0) red4[w] = x;
  __syncthreads();
  return red4[0] + red4[1] + red4[2] + red4[3];
}

// ---------------- K1: normalize -> int8 (1 row/wave) + pair scatter + first-touch compact ----
__global__ void __launch_bounds__(256) norm_pairs_kernel(
    const float* __restrict__ X, signed char* __restrict__ Ei8,
    const int2* __restrict__ pairs, int* pcount, int* partners,
    int* rowlist, int* cnt) {
  const int tid  = threadIdx.x;
  const int lane = tid & 63;
  const int wib  = tid >> 6;
  const int row  = blockIdx.x * 4 + wib;      // grid 2048 -> rows 0..8191

  float4 x = ((const float4*)(X + (size_t)row * DK))[lane];
  float ss = x.x * x.x + x.y * x.y + x.z * x.z + x.w * x.w;
  #pragma unroll
  for (int o = 32; o; o >>= 1) ss += __shfl_xor(ss, o);
  float inv = 127.0f / fmaxf(sqrtf(ss), 1e-8f);
  int c0 = (int)rintf(inv * x.x);
  int c1 = (int)rintf(inv * x.y);
  int c2 = (int)rintf(inv * x.z);
  int c3 = (int)rintf(inv * x.w);
  unsigned u = (unsigned)(c0 & 255) | ((unsigned)(c1 & 255) << 8)
             | ((unsigned)(c2 & 255) << 16) | ((unsigned)(c3 & 255) << 24);
  ((unsigned*)(Ei8 + (size_t)row * DK))[lane] = u;

  const int p = blockIdx.x * 256 + tid;
  if (p < PN) {
    int2 pr = pairs[p];
    int ix = atomicAdd(&pcount[pr.x], 1);
    if (ix == 0) { int q = atomicAdd(cnt, 1); rowlist[q] = pr.x; }   // first touch
    if (ix < MAXP) partners[pr.x * MAXP + ix] = pr.y;
    int iy = atomicAdd(&pcount[pr.y], 1);
    if (iy == 0) { int q = atomicAdd(cnt, 1); rowlist[q] = pr.y; }
    if (iy < MAXP) partners[pr.y * MAXP + iy] = pr.x;
  }
}

// ---------------- K2: pos (1 pair/wave, int8 dot) ----------------
__global__ void __launch_bounds__(256) pos_kernel(
    const signed char* __restrict__ Ei8, const int2* __restrict__ pairs,
    float* __restrict__ pos) {
  const int tid  = threadIdx.x;
  const int lane = tid & 63;
  const int wib  = tid >> 6;
  const int p    = blockIdx.x * 4 + wib;      // grid 1024 -> pairs 0..4095
  int2 pr = pairs[p];
  int a = ((const int*)(Ei8 + (size_t)pr.x * DK))[lane];
  int b = ((const int*)(Ei8 + (size_t)pr.y * DK))[lane];
  int s = 0;
  #pragma unroll
  for (int j = 0; j < 4; ++j) {
    int va = (int)(signed char)(a >> (8 * j));
    int vb = (int)(signed char)(b >> (8 * j));
    s += va * vb;
  }
  #pragma unroll
  for (int o = 32; o; o >>= 1) s += __shfl_xor(s, o);
  if (lane == 0) pos[p] = __expf((float)s * (5.0f / 16129.0f));
}

// ---------------- K3: int8 GEMM, BK=128 -> logit codes ----------------
// dot_i32 = sum Ei8[row].Ei8[col]; cos = dot/127^2.
// code = clamp(trunc(dot*(250/16129) + 128.5), 1, 255); 0 reserved for masked.
// Interleaved out: dword [rowgroup][col] = rows 4g..4g+3 (byte=row%4).
// 128x128 tile, BK=128 (2 K-iters -> 4 barriers), mfma_i32_16x16x64_i8,
// global_load_lds(16B). LDS slot swizzle sl = sg ^ (row&7): fragment
// ds_read_b128 spreads banks (~2 lanes/bank-group, free per m136).
__global__ void __launch_bounds__(256) gemm_code_kernel(
    const signed char* __restrict__ Ei8, const int* __restrict__ rowlist,
    const int* __restrict__ countp, uint32_t* __restrict__ out4) {
  if ((int)blockIdx.y * 128 >= *countp) return;
  __shared__ __align__(16) signed char sA[128 * 128];   // 16 KB
  __shared__ __align__(16) signed char sB[128 * 128];   // 16 KB
  const int tid  = threadIdx.x;
  const int lane = tid & 63;
  const int w    = tid >> 6;
  const int wm   = w >> 1, wn = w & 1;
  const int trow = blockIdx.y * 128;
  const int tcol = blockIdx.x * 128;

  const int srow = tid >> 3;
  const int sl   = tid & 7;
  const int sg   = sl ^ (srow & 7);
  int garow[4], gbrow[4];
  #pragma unroll
  for (int ii = 0; ii < 4; ++ii) {
    garow[ii] = rowlist[trow + ii * 32 + srow];
    gbrow[ii] = tcol + ii * 32 + srow;
  }

  i32x4 acc[4][4];
  #pragma unroll
  for (int i = 0; i < 4; ++i)
    #pragma unroll
    for (int j = 0; j < 4; ++j) {
      i32x4 z = {0, 0, 0, 0};
      acc[i][j] = z;
    }

  for (int kt = 0; kt < 2; ++kt) {
    const int k0 = kt * 128;
    __syncthreads();
    #pragma unroll
    for (int ii = 0; ii < 4; ++ii) {
      gload_lds16(Ei8 + (size_t)garow[ii] * DK + k0 + sg * 16, &sA[ii * 4096 + tid * 16]);
      gload_lds16(Ei8 + (size_t)gbrow[ii] * DK + k0 + sg * 16, &sB[ii * 4096 + tid * 16]);
    }
    __syncthreads();
    #pragma unroll
    for (int h = 0; h < 2; ++h) {
      const int fg = h * 4 + (lane >> 4);     // k-segment 0..7 (16 i8 each)
      i32x4 af[4], bfg[4];
      #pragma unroll
      for (int q = 0; q < 4; ++q) {
        const int ra = wm * 64 + q * 16 + (lane & 15);
        const int rb = wn * 64 + q * 16 + (lane & 15);
        af[q]  = *(const i32x4*)&sA[ra * 128 + (fg ^ (ra & 7)) * 16];
        bfg[q] = *(const i32x4*)&sB[rb * 128 + (fg ^ (rb & 7)) * 16];
      }
      #pragma unroll
      for (int i = 0; i < 4; ++i)
        #pragma unroll
        for (int j = 0; j < 4; ++j)
          acc[i][j] = __builtin_amdgcn_mfma_i32_16x16x64_i8(af[i], bfg[j], acc[i][j], 0, 0, 0);
    }
  }

  const int crow = trow + wm * 64 + (lane >> 4) * 4;  // %4 == 0
  const int ccol = tcol + wn * 64 + (lane & 15);
  const float SCL = 250.0f / 16129.0f;                // (1/beta)/(127^2) in code units
  #pragma unroll
  for (int i = 0; i < 4; ++i) {
    const int gidx = (crow + i * 16) >> 2;
    #pragma unroll
    for (int j = 0; j < 4; ++j) {
      const int col = ccol + j * 16;
      uint32_t u = 0;
      #pragma unroll
      for (int r = 0; r < 4; ++r) {
        int c = (int)fmaf((float)acc[i][j][r], SCL, 128.5f);
        c = c < 1 ? 1 : (c > 255 ? 255 : c);
        u |= (uint32_t)c << (8 * r);
      }
      out4[(size_t)gidx * BN + col] = u;
    }
  }
}

// ---------------- K4: row stats from code histogram ----------------
// One block per group of 4 compacted rows. Code byte == radix bin (uniform in
// logit space -> ~100 occupied bins). One histogram pass, exact select on
// quantized values: S = sum_{bin>b} cnt*val(bin) + need*val(b).
__global__ void __launch_bounds__(256) row_stats4_kernel(
    const uint32_t* __restrict__ expc4, const int* __restrict__ rowlist,
    const int* __restrict__ countp, const int* __restrict__ pcount,
    const int* __restrict__ partners, float* __restrict__ S) {
  __shared__ unsigned hist[4][4][256];   // [wave][r4][bin] = 16 KB
  __shared__ unsigned total[4][256];     // 4 KB
  __shared__ int plist[4][MAXP + 1];
  __shared__ int npl[4];
  __shared__ int growl[4];
  __shared__ int sh[2];
  __shared__ unsigned wtot[4];
  __shared__ float redf[4];
  const int g = blockIdx.x;
  const int cnt = *countp;
  if (g * 4 >= cnt) return;
  const int tid = threadIdx.x, lane = tid & 63, w = tid >> 6;

  uint4 rv[8];
  const uint4* src = (const uint4*)(expc4 + (size_t)g * BN);
  #pragma unroll
  for (int q = 0; q < 8; ++q) rv[q] = src[q * 256 + tid];

  if (tid < 4) {
    int rr = g * 4 + tid;
    int grow = (rr < cnt) ? rowlist[rr] : -1;
    growl[tid] = grow;
    int np = 0;
    if (grow >= 0) {
      np = pcount[grow]; if (np > MAXP) np = MAXP;
      for (int e = 0; e < np; ++e) plist[tid][e] = partners[grow * MAXP + e];
      plist[tid][np] = grow;   // diagonal
      np++;
    }
    npl[tid] = np;
  }
  #pragma unroll
  for (int k = 0; k < 16; ++k) ((unsigned*)hist)[k * 256 + tid] = 0;
  __syncthreads();

  // mask partner/diagonal columns (zero byte -> bin 0, never selected)
  #pragma unroll
  for (int r4 = 0; r4 < 4; ++r4) {
    const int np = npl[r4];
    for (int e = 0; e < np; ++e) {
      int c = plist[r4][e];
      int t = c >> 2;
      if ((t & 255) == tid) {
        unsigned* wp = (unsigned*)&rv[t >> 8];
        wp[c & 3] &= ~(0xFFu << (r4 * 8));
      }
    }
  }

  unsigned* h = (unsigned*)hist[w];
  #pragma unroll
  for (int q = 0; q < 8; ++q) {
    #pragma unroll
    for (int word = 0; word < 4; ++word) {
      unsigned dw = ((const unsigned*)&rv[q])[word];
      atomicAdd(&h[0 * 256 + (dw & 255u)], 1u);
      atomicAdd(&h[1 * 256 + ((dw >> 8) & 255u)], 1u);
      atomicAdd(&h[2 * 256 + ((dw >> 16) & 255u)], 1u);
      atomicAdd(&h[3 * 256 + (dw >> 24)], 1u);
    }
  }
  __syncthreads();
  #pragma unroll
  for (int r4 = 0; r4 < 4; ++r4)
    total[r4][tid] = hist[0][r4][tid] + hist[1][r4][tid] + hist[2][r4][tid] + hist[3][r4][tid];
  __syncthreads();

  const float val = __expf((float)(tid - 128) * QSTEP);
  for (int r4 = 0; r4 < 4; ++r4) {
    find_bin_256(total[r4], RANK_ASC, sh, wtot);
    const int b    = sh[0];
    const int need = (int)total[r4][b] - sh[1];
    float contrib = (tid > b) ? (float)total[r4][tid] * val
                  : (tid == b) ? (float)need * val : 0.f;
    #pragma unroll
    for (int o = 32; o; o >>= 1) contrib += __shfl_xor(contrib, o);
    __syncthreads();
    if (lane == 0) redf[w] = contrib;
    __syncthreads();
    if (tid == 0 && growl[r4] >= 0)
      S[growl[r4]] = redf[0] + redf[1] + redf[2] + redf[3];
    __syncthreads();
  }
}

// ---------------- K5: finale ----------------
// Exact radix select of pos rank 819 -> thr; factorized loss:
// log1p(S/p) = logS - logp + p/S - p^2/(2S^2) + O((p/S)^3), p/S <~ 3e-4
// loss = (n*T - 2P*sl + sp*U - 0.5*sp2*V) / (2P)
__global__ void __launch_bounds__(256) finale_kernel(
    const float* __restrict__ pos, const int2* __restrict__ pairs,
    const float* __restrict__ S, float* __restrict__ out) {
  __shared__ uint32_t v[PN];
  __shared__ unsigned hist[256];
  __shared__ int sh[2];
  __shared__ unsigned wtot[4];
  __shared__ float red4[4];
  const int tid = threadIdx.x;
  for (int i = tid; i < PN; i += 256) v[i] = ((const uint32_t*)pos)[i];
  __syncthreads();
  int rank = 819;                 // 0.2 * 4095 exactly
  uint32_t prefix = 0;
  for (int pass = 0; pass < 4; ++pass) {
    const int shift = 24 - pass * 8;
    hist[tid] = 0;
    __syncthreads();
    for (int i = tid; i < PN; i += 256) {
      uint32_t x = v[i];
      bool match = (pass == 0) || ((x >> (shift + 8)) == (prefix >> (shift + 8)));
      if (match) atomicAdd(&hist[(x >> shift) & 255u], 1u);
    }
    __syncthreads();
    find_bin_256(hist, rank, sh, wtot);
    prefix |= ((uint32_t)sh[0]) << shift;
    rank = sh[1];
    __syncthreads();
  }
  float thr; __builtin_memcpy(&thr, &prefix, 4);

  float n = 0.f, sl = 0.f, sp = 0.f, sp2 = 0.f;
  for (int r = tid; r < PN; r += 256) {
    float p; uint32_t b = v[r]; __builtin_memcpy(&p, &b, 4);
    if (p <= thr) { n += 1.f; sl += __logf(p); sp += p; sp2 += p * p; }
  }
  float t = 0.f, u = 0.f, vv = 0.f;
  for (int c = tid; c < PN; c += 256) {
    int2 pr = pairs[c];
    float s1 = S[pr.x], s2 = S[pr.y];
    float i1 = 1.f / s1, i2 = 1.f / s2;
    t += __logf(s1) + __logf(s2);
    u += i1 + i2;
    vv += i1 * i1 + i2 * i2;
  }
  const float N   = block_sum4(n, red4);
  const float SL  = block_sum4(sl, red4);
  const float SP  = block_sum4(sp, red4);
  const float SP2 = block_sum4(sp2, red4);
  const float T   = block_sum4(t, red4);
  const float U   = block_sum4(u, red4);
  const float V   = block_sum4(vv, red4);
  if (tid == 0) {
    double num = (double)N * T - 2.0 * (double)PN * (double)SL
               + (double)SP * U - 0.5 * (double)SP2 * V;
    out[0] = (float)(num / (2.0 * (double)PN));
  }
}

// ---------------------------------------------------------------- launch
extern "C" void kernel_launch(void* const* d_in, const int* in_sizes, int n_in,
                              void* d_out, int out_size, void* d_ws, size_t ws_size,
                              hipStream_t stream) {
  const float* emb  = (const float*)d_in[0];
  const int2* pairs = (const int2*)d_in[1];
  float* out = (float*)d_out;

  // ws layout: [pcnt | rlist | cnt] contiguous -> ONE async memset clears all
  char* w = (char*)d_ws;
  size_t off = 0;
  int*         pcnt  = (int*)(w + off);         off += (size_t)BN * 4;
  int*         rlist = (int*)(w + off);         off += (size_t)BN * 4;
  int*         cnt   = (int*)(w + off);         off += 256;
  signed char* Ei8   = (signed char*)(w + off); off += (size_t)BN * DK;      // 2 MB
  float*       S     = (float*)(w + off);       off += (size_t)BN * 4;
  float*       pos   = (float*)(w + off);       off += (size_t)PN * 4;
  int*         parts = (int*)(w + off);         off += (size_t)BN * MAXP * 4; // 512 KB
  uint32_t*    out4  = (uint32_t*)(w + off);    off += (size_t)(BN / 4) * BN * 4; // 67 MB

  hipMemsetAsync(pcnt, 0, (size_t)BN * 8 + 256, stream);   // pcnt + rlist + cnt
  norm_pairs_kernel<<<BN / 4, 256, 0, stream>>>(emb, Ei8, pairs, pcnt, parts, rlist, cnt);
  pos_kernel<<<PN / 4, 256, 0, stream>>>(Ei8, pairs, pos);
  gemm_code_kernel<<<dim3(BN / 128, BN / 128), 256, 0, stream>>>(Ei8, rlist, cnt, out4);
  row_stats4_kernel<<<BN / 4, 256, 0, stream>>>(out4, rlist, cnt, pcnt, parts, S);
  finale_kernel<<<1, 256, 0, stream>>>(pos, pairs, S, out);
}